// Round 1
// baseline (52.134 us; speedup 1.0000x reference)
//
#include <hip/hip_runtime.h>

// out[b] = SCALE^2 * ( dot(x[b,:], colsum) + sum(bias) ),  colsum[i] = sum_o W[o,i]
// Collapses the GEMM (y = x W^T + b; out = 0.01 * y.sum(-1)) via reassociation.

constexpr int IN_DIM = 2048;
constexpr int BATCH  = 8192;
constexpr float SCALE2 = 0.01f;  // SCALE * SCALE

// ---------------------------------------------------------------------------
// K1: partial column sums of W.
// grid = RB blocks, 256 threads. Block rb sums rows [rb*rows_per_blk, ...)
// Each thread owns cols [4t,4t+4) and [1024+4t, 1024+4t+4) via float4.
// partial[rb*IN_DIM + col] = sum over that block's rows of W[row][col].
// ---------------------------------------------------------------------------
__global__ void colsum_partial_kernel(const float* __restrict__ W,
                                      float* __restrict__ partial,
                                      int rows_per_blk) {
    const int t  = threadIdx.x;          // 0..255
    const int rb = blockIdx.x;
    const size_t row0 = (size_t)rb * rows_per_blk;

    float4 acc0 = {0.f, 0.f, 0.f, 0.f};
    float4 acc1 = {0.f, 0.f, 0.f, 0.f};

    const float* Wp = W + row0 * IN_DIM;
    for (int r = 0; r < rows_per_blk; ++r) {
        const float4* row = reinterpret_cast<const float4*>(Wp + (size_t)r * IN_DIM);
        float4 a = row[t];        // cols [4t, 4t+4)
        float4 b = row[256 + t];  // cols [1024+4t, ...)
        acc0.x += a.x; acc0.y += a.y; acc0.z += a.z; acc0.w += a.w;
        acc1.x += b.x; acc1.y += b.y; acc1.z += b.z; acc1.w += b.w;
    }

    float4* outp = reinterpret_cast<float4*>(partial + (size_t)rb * IN_DIM);
    outp[t]       = acc0;
    outp[256 + t] = acc1;
}

// ---------------------------------------------------------------------------
// K2: reduce partials -> wsum (pre-scaled by SCALE2); block 8 reduces bias.
// grid = 9 blocks x 256 threads.
// ---------------------------------------------------------------------------
__global__ void reduce_wsum_kernel(const float* __restrict__ partial,
                                   const float* __restrict__ bias,
                                   float* __restrict__ wsum,
                                   float* __restrict__ bsum,
                                   int rb_count) {
    if (blockIdx.x < 8) {
        const int col = blockIdx.x * 256 + threadIdx.x;  // 0..2047
        float s = 0.f;
        for (int rb = 0; rb < rb_count; ++rb)
            s += partial[(size_t)rb * IN_DIM + col];
        wsum[col] = s * SCALE2;
    } else {
        // bias sum: 2048 elements, 256 threads x 8 each, then block reduce.
        const int t = threadIdx.x;
        float s = 0.f;
        #pragma unroll
        for (int k = 0; k < 8; ++k)
            s += bias[t + k * 256];
        // 64-lane wave reduce
        #pragma unroll
        for (int off = 32; off > 0; off >>= 1)
            s += __shfl_down(s, off, 64);
        __shared__ float wsums[4];
        const int lane = t & 63;
        const int wid  = t >> 6;
        if (lane == 0) wsums[wid] = s;
        __syncthreads();
        if (t == 0) {
            float total = wsums[0] + wsums[1] + wsums[2] + wsums[3];
            bsum[0] = total * SCALE2;
        }
    }
}

// ---------------------------------------------------------------------------
// K3: matvec. One wave (64 lanes) per row of x. block = 256 (4 waves),
// grid = BATCH/4. Each lane: 8 x float4 coalesced loads, then shfl reduce.
// out[row] = dot(x[row,:], wsum) + bsum   (wsum/bsum already scaled)
// ---------------------------------------------------------------------------
__global__ void matvec_kernel(const float* __restrict__ x,
                              const float* __restrict__ wsum,
                              const float* __restrict__ bsum,
                              float* __restrict__ out) {
    const int lane = threadIdx.x & 63;
    const int wid  = threadIdx.x >> 6;               // 0..3
    const int row  = blockIdx.x * 4 + wid;           // 0..BATCH-1

    const float4* xr = reinterpret_cast<const float4*>(x + (size_t)row * IN_DIM);
    const float4* wv = reinterpret_cast<const float4*>(wsum);

    float acc = 0.f;
    #pragma unroll
    for (int k = 0; k < 8; ++k) {
        float4 a = xr[lane + k * 64];   // byte offset 16*lane: fully coalesced
        float4 w = wv[lane + k * 64];   // L2-resident after first wave
        acc += a.x * w.x + a.y * w.y + a.z * w.z + a.w * w.w;
    }

    #pragma unroll
    for (int off = 32; off > 0; off >>= 1)
        acc += __shfl_down(acc, off, 64);

    if (lane == 0)
        out[row] = acc + bsum[0];
}

extern "C" void kernel_launch(void* const* d_in, const int* in_sizes, int n_in,
                              void* d_out, int out_size, void* d_ws, size_t ws_size,
                              hipStream_t stream) {
    const float* x    = (const float*)d_in[0];   // [8192, 2048]
    const float* W    = (const float*)d_in[1];   // [2048, 2048] (out, in)
    const float* bias = (const float*)d_in[2];   // [2048]
    float* out = (float*)d_out;                  // [8192]
    float* ws  = (float*)d_ws;

    // Workspace layout: partial[RB][2048] | wsum[2048] | bsum[1]
    // Prefer RB=128 (1 MB + 8 KB); fall back to RB=64 if ws is small.
    int rb = 64;
    if (ws_size >= (size_t)(128 * IN_DIM + IN_DIM + 1) * sizeof(float)) rb = 128;
    const int rows_per_blk = IN_DIM / rb;

    float* partial = ws;
    float* wsum    = ws + (size_t)rb * IN_DIM;
    float* bsum    = wsum + IN_DIM;

    colsum_partial_kernel<<<rb, 256, 0, stream>>>(W, partial, rows_per_blk);
    reduce_wsum_kernel<<<9, 256, 0, stream>>>(partial, bias, wsum, bsum, rb);
    matvec_kernel<<<BATCH / 4, 256, 0, stream>>>(x, wsum, bsum, out);
}